// Round 21
// baseline (143.544 us; speedup 1.0000x reference)
//
#include <hip/hip_runtime.h>
#include <math.h>

#define NLB 96          // L*B = 3*32
#define CC  256
#define PP  49
#define QQ  961
#define QP  1024
#define TEMP_INV 40.0f  // 1/0.025
#define BN_EPS 1e-5f

#define N1 (NLB*CC*PP)  // 1,204,224
#define N2 (NLB*CC*QQ)  // 23,617,536

// ===== K1 prep_z: inv1[p], w[c] = sum_p inv1[p] f1[c,p] =====================
__global__ __launch_bounds__(256) void prep_z(
    const float* __restrict__ zf, float* __restrict__ inv1_ws,
    float* __restrict__ w_ws)
{
    const int lb = blockIdx.x;
    const int tid = threadIdx.x;
    __shared__ float f1L[CC * PP];
    __shared__ float inv1L[PP];
    const float* __restrict__ f1 = zf + (size_t)lb * CC * PP;
    for (int i = tid; i < CC * PP; i += 256) f1L[i] = f1[i];
    __syncthreads();
    if (tid < PP) {
        float ss = 0.f;
        for (int c = 0; c < CC; ++c) { const float x = f1L[c * PP + tid]; ss = fmaf(x, x, ss); }
        const float iv = 1.0f / fmaxf(sqrtf(ss), 1e-12f);
        inv1L[tid] = iv;
        inv1_ws[lb * 64 + tid] = iv;
    }
    __syncthreads();
    {
        float s = 0.f;
#pragma unroll
        for (int p = 0; p < PP; ++p) s = fmaf(inv1L[p], f1L[tid * PP + p], s);
        w_ws[lb * CC + tid] = s;
    }
}

// ===== K2 xjoint1: ONE kernel: ss/dc -> inv2, mcol; then v partials =========
// grid (4 qg, 96 lb), 256 threads. Phase A: stream 16c x 256q LDS tiles,
// thread-per-q ss/dc in registers -> inv2[q], mcol[q] written in-block
// (replaces xpass1 + finq). Phase B: re-stream same tiles (L3-hot) for
// wave-per-row weighted row sums -> vp[(lb,qg)][c] (replaces vpass).
__global__ __launch_bounds__(256) void xjoint1(
    const float* __restrict__ xf, const float* __restrict__ w_ws,
    float* __restrict__ inv2_ws, float* __restrict__ mcol_ws,
    float* __restrict__ vp)
{
    const int qg = blockIdx.x;       // 0..3
    const int lb = blockIdx.y;
    const int tid  = threadIdx.x;
    const int lane = tid & 63;
    const int wave = tid >> 6;       // 0..3
    const int q  = qg * 256 + tid;
    const bool qv = (q < QQ);
    const int qc = qv ? q : QQ - 1;

    __shared__ float wL[CC];
    __shared__ float wqL[256];
    __shared__ __align__(16) float tile[16 * 264];

    wL[tid] = w_ws[lb * CC + tid];

    const float* __restrict__ base = xf + (size_t)lb * CC * QQ + qc;

    // phase A: ss, dc per q
    float ss = 0.f, dc = 0.f;
    for (int c0 = 0; c0 < CC; c0 += 16) {
        __syncthreads();
#pragma unroll
        for (int r = 0; r < 16; ++r)
            tile[r * 264 + tid] = base[(size_t)(c0 + r) * QQ];
        __syncthreads();
#pragma unroll
        for (int r = 0; r < 16; ++r) {
            const float x = tile[r * 264 + tid];
            ss = fmaf(x, x, ss);
            dc = fmaf(wL[c0 + r], x, dc);
        }
    }
    const float iv2 = 1.0f / fmaxf(sqrtf(ss), 1e-12f);
    if (qv) {
        inv2_ws[lb * QP + q] = iv2;
        mcol_ws[lb * QP + q] = dc * iv2 * (1.0f / PP);
    }
    __syncthreads();
    wqL[tid] = qv ? iv2 : 0.f;

    float* __restrict__ vpo = vp + ((size_t)(lb * 4 + qg)) * CC;
    // phase B: v partials (re-read, L3-hot)
    for (int c0 = 0; c0 < CC; c0 += 16) {
        __syncthreads();
#pragma unroll
        for (int r = 0; r < 16; ++r)
            tile[r * 264 + tid] = base[(size_t)(c0 + r) * QQ];
        __syncthreads();
#pragma unroll
        for (int rr = 0; rr < 4; ++rr) {
            const int r = wave + rr * 4;
            float s = 0.f;
#pragma unroll
            for (int j = 0; j < 4; ++j)
                s = fmaf(tile[r * 264 + j * 64 + lane], wqL[j * 64 + lane], s);
            for (int off = 32; off > 0; off >>= 1) s += __shfl_xor(s, off, 64);
            if (lane == 0) vpo[c0 + r] = s;
        }
    }
}

// ===== K3 mid: mrow, MLPs -> wgt (t2a*inv2), wb =============================
__global__ __launch_bounds__(512) void mid_kernel(
    const float* __restrict__ zf, const float* __restrict__ vp,
    const float* __restrict__ inv1_ws, const float* __restrict__ mcol_ws,
    const float* __restrict__ inv2_ws,
    const float* __restrict__ W1, const float* __restrict__ b1,
    const float* __restrict__ g1, const float* __restrict__ bb1,
    const float* __restrict__ rm1, const float* __restrict__ rv1,
    const float* __restrict__ W2, const float* __restrict__ b2,
    const float* __restrict__ W3, const float* __restrict__ b3,
    const float* __restrict__ g3, const float* __restrict__ bb3,
    const float* __restrict__ rm3, const float* __restrict__ rv3,
    const float* __restrict__ W4, const float* __restrict__ b4,
    float* __restrict__ wgt_ws, float* __restrict__ wb_ws)
{
    const int lb = blockIdx.x;
    const int tid = threadIdx.x;
    __shared__ float f1L[CC * PP];
    __shared__ float inv1L[64], vL[CC], mrowL[PP];
    __shared__ float mcolL[QQ];
    __shared__ float taL[31], tbL[7], t2bL[PP];

    const float* __restrict__ f1 = zf + (size_t)lb * CC * PP;
    for (int i = tid; i < CC * PP; i += 512) f1L[i] = f1[i];
    if (tid < 64) inv1L[tid] = inv1_ws[lb * 64 + tid];
    if (tid < CC) {
        float s = 0.f;
#pragma unroll
        for (int qg = 0; qg < 4; ++qg) s += vp[((size_t)(lb * 4 + qg)) * CC + tid];
        vL[tid] = s;
    }
    for (int q = tid; q < QQ; q += 512) mcolL[q] = mcol_ws[lb * QP + q];
    __syncthreads();

    if (tid < PP) {
        float s = 0.f;
        for (int c = 0; c < CC; ++c) s = fmaf(f1L[c * PP + tid], vL[c], s);
        mrowL[tid] = s * inv1L[tid] * (1.0f / QQ);
    }
    if (tid < 31 * 16) {
        const int k = tid >> 4, sub = tid & 15;
        float s = 0.f;
        for (int q = sub; q < QQ; q += 16) s = fmaf(mcolL[q], W1[k * QQ + q], s);
        s += __shfl_xor(s, 1, 64); s += __shfl_xor(s, 2, 64);
        s += __shfl_xor(s, 4, 64); s += __shfl_xor(s, 8, 64);
        if (sub == 0) {
            float t = s + b1[k];
            t = (t - rm1[k]) * rsqrtf(rv1[k] + BN_EPS) * g1[k] + bb1[k];
            taL[k] = fmaxf(t, 0.f);
        }
    }
    __syncthreads();
    if (tid < 7 * 8) {
        const int k = tid >> 3, sub = tid & 7;
        float s = 0.f;
        for (int p = sub; p < PP; p += 8) s = fmaf(mrowL[p], W3[k * PP + p], s);
        s += __shfl_xor(s, 1, 64); s += __shfl_xor(s, 2, 64); s += __shfl_xor(s, 4, 64);
        if (sub == 0) {
            float t = s + b3[k];
            t = (t - rm3[k]) * rsqrtf(rv3[k] + BN_EPS) * g3[k] + bb3[k];
            tbL[k] = fmaxf(t, 0.f);
        }
    }
    __syncthreads();
    if (tid < PP) {
        float s = b4[tid];
#pragma unroll
        for (int k = 0; k < 7; ++k) s = fmaf(tbL[k], W4[tid * 7 + k], s);
        t2bL[tid] = s;
    }
    for (int q = tid; q < QQ; q += 512) {
        float s = b2[q];
#pragma unroll
        for (int k = 0; k < 31; ++k) s = fmaf(taL[k], W2[q * 31 + k], s);
        wgt_ws[lb * QP + q] = s * inv2_ws[lb * QP + q];
    }
    __syncthreads();
    if (tid < CC) {
        float s = 0.f;
#pragma unroll
        for (int p = 0; p < PP; ++p) s = fmaf(inv1L[p] * t2bL[p], f1L[tid * PP + p], s);
        wb_ws[lb * CC + tid] = s;
    }
}

// ===== K4 xjoint: ONE xf sweep -> s2 partials + vb partials =================
__global__ __launch_bounds__(256) void xjoint(
    const float* __restrict__ xf, const float* __restrict__ wb_ws,
    const float* __restrict__ wgt_ws,
    float* __restrict__ s2p, float* __restrict__ vbp)
{
    const int qg = blockIdx.x;       // 0..3
    const int ch = blockIdx.y;       // 0..1
    const int lb = blockIdx.z;
    const int tid  = threadIdx.x;
    const int lane = tid & 63;
    const int wave = tid >> 6;       // 0..3
    const int q  = qg * 256 + tid;
    const bool qv = (q < QQ);
    const int qc = qv ? q : QQ - 1;

    __shared__ float wbL[128];
    __shared__ float wgtL[256];
    __shared__ __align__(16) float tile[16 * 264];

    if (tid < 128) wbL[tid] = wb_ws[lb * CC + ch * 128 + tid];
    wgtL[tid] = qv ? wgt_ws[lb * QP + q] : 0.f;

    const float* __restrict__ base =
        xf + (size_t)lb * CC * QQ + (size_t)(ch * 128) * QQ + qc;
    float* __restrict__ vbpo = vbp + ((size_t)(lb * 8 + ch * 4 + qg)) * 128;

    float dwb = 0.f;
    for (int c0 = 0; c0 < 128; c0 += 16) {
        __syncthreads();
#pragma unroll
        for (int r = 0; r < 16; ++r)
            tile[r * 264 + tid] = base[(size_t)(c0 + r) * QQ];
        __syncthreads();
#pragma unroll
        for (int r = 0; r < 16; ++r)
            dwb = fmaf(wbL[c0 + r], tile[r * 264 + tid], dwb);
#pragma unroll
        for (int rr = 0; rr < 4; ++rr) {
            const int r = wave + rr * 4;
            float s = 0.f;
#pragma unroll
            for (int j = 0; j < 4; ++j)
                s = fmaf(tile[r * 264 + j * 64 + lane], wgtL[j * 64 + lane], s);
            for (int off = 32; off > 0; off >>= 1) s += __shfl_xor(s, off, 64);
            if (lane == 0) vbpo[c0 + r] = s;
        }
    }
    if (qv) s2p[((size_t)ch * NLB + lb) * QP + q] = dwb;
}

// ===== K5 fin: s1 from vb partials; s2 from partials; softmaxes =============
__global__ __launch_bounds__(512) void fin_kernel(
    const float* __restrict__ zf, const float* __restrict__ vbp,
    const float* __restrict__ inv1_ws, const float* __restrict__ s2p,
    const float* __restrict__ inv2_ws,
    float* __restrict__ att1_ws, float* __restrict__ att2_ws)
{
    const int lb = blockIdx.x;
    const int tid = threadIdx.x;
    const int lane = tid & 63;
    const int wv = tid >> 6;
    __shared__ float f1L[CC * PP];
    __shared__ float vbL[CC], inv1L[64], s1L[PP];
    __shared__ float s2L[QQ];
    __shared__ float redM[8], redS[8];

    const float* __restrict__ f1 = zf + (size_t)lb * CC * PP;
    for (int i = tid; i < CC * PP; i += 512) f1L[i] = f1[i];
    if (tid < CC) {
        const int ch = tid >> 7;           // which c-half this c belongs to
        const int co = tid & 127;
        float s = 0.f;
#pragma unroll
        for (int qg = 0; qg < 4; ++qg)
            s += vbp[((size_t)(lb * 8 + ch * 4 + qg)) * 128 + co];
        vbL[tid] = s;
    }
    if (tid >= 256 && tid < 320) inv1L[tid - 256] = inv1_ws[lb * 64 + tid - 256];
    for (int q = tid; q < QQ; q += 512)
        s2L[q] = (s2p[((size_t)0 * NLB + lb) * QP + q] +
                  s2p[((size_t)1 * NLB + lb) * QP + q]) *
                 inv2_ws[lb * QP + q] * (1.0f / PP) * TEMP_INV;
    __syncthreads();

    if (tid < PP) {
        float s = 0.f;
        for (int c = 0; c < CC; ++c) s = fmaf(f1L[c * PP + tid], vbL[c], s);
        s1L[tid] = s * inv1L[tid] * (1.0f / QQ) * TEMP_INV;
    }
    __syncthreads();

    if (wv == 0) {
        const float v = (lane < PP) ? s1L[lane] : -3.4e38f;
        float m = v;
        for (int off = 32; off > 0; off >>= 1) m = fmaxf(m, __shfl_xor(m, off, 64));
        const float e = (lane < PP) ? expf(v - m) : 0.f;
        float sum = e;
        for (int off = 32; off > 0; off >>= 1) sum += __shfl_xor(sum, off, 64);
        if (lane < PP) att1_ws[lb * PP + lane] = e / sum + 1.0f;
    }

    float lm = -3.4e38f;
    for (int q = tid; q < QQ; q += 512) lm = fmaxf(lm, s2L[q]);
    for (int off = 32; off > 0; off >>= 1) lm = fmaxf(lm, __shfl_xor(lm, off, 64));
    if (lane == 0) redM[wv] = lm;
    __syncthreads();
    float gm = redM[0];
#pragma unroll
    for (int i = 1; i < 8; ++i) gm = fmaxf(gm, redM[i]);
    float ls = 0.f;
    for (int q = tid; q < QQ; q += 512) ls += expf(s2L[q] - gm);
    for (int off = 32; off > 0; off >>= 1) ls += __shfl_xor(ls, off, 64);
    if (lane == 0) redS[wv] = ls;
    __syncthreads();
    float tot = 0.f;
#pragma unroll
    for (int i = 0; i < 8; ++i) tot += redS[i];
    const float rinv = 1.0f / tot;
    for (int q = tid; q < QQ; q += 512)
        att2_ws[lb * QQ + q] = expf(s2L[q] - gm) * rinv + 1.0f;
}

// ===== scale: out = in * att[lb, inner] =====================================
template <int INNER>
__global__ __launch_bounds__(256) void scale_kernel(
    const float* __restrict__ in, const float* __restrict__ att,
    float* __restrict__ out, int n4)
{
    const int i = blockIdx.x * 256 + threadIdx.x;
    if (i >= n4) return;
    const float4 v = reinterpret_cast<const float4*>(in)[i];
    const float* vv = reinterpret_cast<const float*>(&v);
    float4 o;
    float* ov = reinterpret_cast<float*>(&o);
    const int g = i * 4;
#pragma unroll
    for (int j = 0; j < 4; ++j) {
        const int gg = g + j;
        const int lb = gg / (CC * INNER);
        const int x  = gg % INNER;
        ov[j] = vv[j] * att[lb * INNER + x];
    }
    reinterpret_cast<float4*>(out)[i] = o;
}

extern "C" void kernel_launch(void* const* d_in, const int* in_sizes, int n_in,
                              void* d_out, int out_size, void* d_ws, size_t ws_size,
                              hipStream_t stream)
{
    const float* zf  = (const float*)d_in[0];
    const float* xf  = (const float*)d_in[1];
    const float* W1  = (const float*)d_in[2];
    const float* b1  = (const float*)d_in[3];
    const float* g1  = (const float*)d_in[4];
    const float* bb1 = (const float*)d_in[5];
    const float* rm1 = (const float*)d_in[6];
    const float* rv1 = (const float*)d_in[7];
    const float* W2  = (const float*)d_in[8];
    const float* b2  = (const float*)d_in[9];
    const float* W3  = (const float*)d_in[10];
    const float* b3  = (const float*)d_in[11];
    const float* g3  = (const float*)d_in[12];
    const float* bb3 = (const float*)d_in[13];
    const float* rm3 = (const float*)d_in[14];
    const float* rv3 = (const float*)d_in[15];
    const float* W4  = (const float*)d_in[16];
    const float* b4  = (const float*)d_in[17];

    float* ws = (float*)d_ws;
    float* w    = ws;                          // 96*256
    float* wb   = w    + (size_t)NLB * CC;     // 96*256
    float* inv1 = wb   + (size_t)NLB * CC;     // 96*64
    float* inv2 = inv1 + (size_t)NLB * 64;     // 96*1024
    float* mcol = inv2 + (size_t)NLB * QP;     // 96*1024
    float* wgt  = mcol + (size_t)NLB * QP;     // 96*1024
    float* att1 = wgt  + (size_t)NLB * QP;     // 96*49
    float* att2 = att1 + (size_t)NLB * PP;     // 96*961
    float* s2p  = att2 + (size_t)NLB * QQ;     // 2*96*1024
    float* vp   = s2p  + (size_t)2 * NLB * QP; // 96*4*256
    float* vbp  = vp   + (size_t)NLB * 4 * CC; // 96*8*128

    float* out1 = (float*)d_out;
    float* out2 = out1 + N1;

    prep_z<<<NLB, 256, 0, stream>>>(zf, inv1, w);

    dim3 g1q(4, NLB);
    xjoint1<<<g1q, 256, 0, stream>>>(xf, w, inv2, mcol, vp);

    mid_kernel<<<NLB, 512, 0, stream>>>(zf, vp, inv1, mcol, inv2,
        W1, b1, g1, bb1, rm1, rv1, W2, b2,
        W3, b3, g3, bb3, rm3, rv3, W4, b4,
        wgt, wb);

    dim3 gqs(4, 2, NLB);
    xjoint<<<gqs, 256, 0, stream>>>(xf, wb, wgt, s2p, vbp);

    fin_kernel<<<NLB, 512, 0, stream>>>(zf, vbp, inv1, s2p, inv2, att1, att2);

    const int n4_1 = N1 / 4;
    const int n4_2 = N2 / 4;
    scale_kernel<PP><<<(n4_1 + 255) / 256, 256, 0, stream>>>(zf, att1, out1, n4_1);
    scale_kernel<QQ><<<(n4_2 + 255) / 256, 256, 0, stream>>>(xf, att2, out2, n4_2);
}

// Round 22
// 133.373 us; speedup vs baseline: 1.0763x; 1.0763x over previous
//
#include <hip/hip_runtime.h>
#include <math.h>

#define NLB 96          // L*B = 3*32
#define CC  256
#define PP  49
#define QQ  961
#define QP  1024
#define TEMP_INV 40.0f  // 1/0.025
#define BN_EPS 1e-5f

#define N1 (NLB*CC*PP)  // 1,204,224
#define N2 (NLB*CC*QQ)  // 23,617,536

// ===== K1 prep_z: inv1[p], w[c] = sum_p inv1[p] f1[c,p] =====================
__global__ __launch_bounds__(256) void prep_z(
    const float* __restrict__ zf, float* __restrict__ inv1_ws,
    float* __restrict__ w_ws)
{
    const int lb = blockIdx.x;
    const int tid = threadIdx.x;
    __shared__ float f1L[CC * PP];
    __shared__ float inv1L[PP];
    const float* __restrict__ f1 = zf + (size_t)lb * CC * PP;
    for (int i = tid; i < CC * PP; i += 256) f1L[i] = f1[i];
    __syncthreads();
    if (tid < PP) {
        float ss = 0.f;
        for (int c = 0; c < CC; ++c) { const float x = f1L[c * PP + tid]; ss = fmaf(x, x, ss); }
        const float iv = 1.0f / fmaxf(sqrtf(ss), 1e-12f);
        inv1L[tid] = iv;
        inv1_ws[lb * 64 + tid] = iv;
    }
    __syncthreads();
    {
        float s = 0.f;
#pragma unroll
        for (int p = 0; p < PP; ++p) s = fmaf(inv1L[p], f1L[tid * PP + p], s);
        w_ws[lb * CC + tid] = s;
    }
}

// ===== K2 xpass1: partial ss / w-dot per (q, c-half). Barrier-free stream ===
__global__ __launch_bounds__(256) void xpass1(
    const float* __restrict__ xf, const float* __restrict__ w_ws,
    float* __restrict__ ssp, float* __restrict__ dcp)
{
    const int qg = blockIdx.x;       // 0..3
    const int ch = blockIdx.y;       // 0..1 (c half)
    const int lb = blockIdx.z;
    const int tid = threadIdx.x;
    const int q  = qg * 256 + tid;
    const bool qv = (q < QQ);
    const int qc = qv ? q : QQ - 1;

    __shared__ float wL[128];
    if (tid < 128) wL[tid] = w_ws[lb * CC + ch * 128 + tid];
    __syncthreads();

    const float* __restrict__ base =
        xf + (size_t)lb * CC * QQ + (size_t)(ch * 128) * QQ + qc;

    float ss = 0.f, dc = 0.f;
    for (int c0 = 0; c0 < 128; c0 += 16) {
        float x[16];
#pragma unroll
        for (int j = 0; j < 16; ++j) x[j] = base[(size_t)(c0 + j) * QQ];
#pragma unroll
        for (int j = 0; j < 16; ++j) {
            ss = fmaf(x[j], x[j], ss);
            dc = fmaf(wL[c0 + j], x[j], dc);
        }
    }
    if (qv) {
        ssp[((size_t)ch * NLB + lb) * QP + q] = ss;
        dcp[((size_t)ch * NLB + lb) * QP + q] = dc;
    }
}

// ===== K3 vpass: v[c] partials; computes inv2 locally from ssp (no finq) ====
__global__ __launch_bounds__(512) void vpass_kernel(
    const float* __restrict__ xf, const float* __restrict__ ssp,
    float* __restrict__ vp)
{
    const int cb = blockIdx.x;       // 0..3 (64 c each)
    const int lb = blockIdx.y;
    const int tid  = threadIdx.x;
    const int lane = tid & 63;
    const int wave = tid >> 6;       // 0..7

    __shared__ float wqL[QP];
    for (int i = tid; i < QP; i += 512) {
        float w = 0.f;
        if (i < QQ) {
            const float ss = ssp[((size_t)0 * NLB + lb) * QP + i] +
                             ssp[((size_t)1 * NLB + lb) * QP + i];
            w = 1.0f / fmaxf(sqrtf(ss), 1e-12f);
        }
        wqL[i] = w;
    }
    __syncthreads();

    const float* __restrict__ f2 = xf + (size_t)lb * CC * QQ;

#pragma unroll
    for (int r = 0; r < 8; ++r) {
        const int c = cb * 64 + wave * 8 + r;
        const float* __restrict__ row = f2 + (size_t)c * QQ;
        float x[16];
#pragma unroll
        for (int j = 0; j < 16; ++j) {
            const int qi = j * 64 + lane;
            x[j] = row[qi < QQ ? qi : QQ - 1];   // clamp; pad weight is 0
        }
        float s = 0.f;
#pragma unroll
        for (int j = 0; j < 16; ++j) s = fmaf(x[j], wqL[j * 64 + lane], s);
        for (int off = 32; off > 0; off >>= 1) s += __shfl_xor(s, off, 64);
        if (lane == 0) vp[((size_t)(lb * 4 + cb)) * 64 + wave * 8 + r] = s;
    }
}

// ===== K4 mid: mcol/inv2 from partials; mrow; MLPs -> wgt, wb; inv2_ws ======
__global__ __launch_bounds__(512) void mid_kernel(
    const float* __restrict__ zf, const float* __restrict__ vp,
    const float* __restrict__ inv1_ws,
    const float* __restrict__ ssp, const float* __restrict__ dcp,
    const float* __restrict__ W1, const float* __restrict__ b1,
    const float* __restrict__ g1, const float* __restrict__ bb1,
    const float* __restrict__ rm1, const float* __restrict__ rv1,
    const float* __restrict__ W2, const float* __restrict__ b2,
    const float* __restrict__ W3, const float* __restrict__ b3,
    const float* __restrict__ g3, const float* __restrict__ bb3,
    const float* __restrict__ rm3, const float* __restrict__ rv3,
    const float* __restrict__ W4, const float* __restrict__ b4,
    float* __restrict__ wgt_ws, float* __restrict__ wb_ws,
    float* __restrict__ inv2_ws)
{
    const int lb = blockIdx.x;
    const int tid = threadIdx.x;
    __shared__ float f1L[CC * PP];
    __shared__ float inv1L[64], vL[CC], mrowL[PP];
    __shared__ float mcolL[QQ];
    __shared__ float i2L[QQ];
    __shared__ float taL[31], tbL[7], t2bL[PP];

    const float* __restrict__ f1 = zf + (size_t)lb * CC * PP;
    for (int i = tid; i < CC * PP; i += 512) f1L[i] = f1[i];
    if (tid < 64) inv1L[tid] = inv1_ws[lb * 64 + tid];
    if (tid < CC) {
        const int cb = tid >> 6, co = tid & 63;
        vL[tid] = vp[((size_t)(lb * 4 + cb)) * 64 + co];
    }
    for (int q = tid; q < QQ; q += 512) {
        const float ss = ssp[((size_t)0 * NLB + lb) * QP + q] +
                         ssp[((size_t)1 * NLB + lb) * QP + q];
        const float dc = dcp[((size_t)0 * NLB + lb) * QP + q] +
                         dcp[((size_t)1 * NLB + lb) * QP + q];
        const float iv2 = 1.0f / fmaxf(sqrtf(ss), 1e-12f);
        i2L[q] = iv2;
        mcolL[q] = dc * iv2 * (1.0f / PP);
        inv2_ws[lb * QP + q] = iv2;      // single writer, consumed by fin
    }
    __syncthreads();

    if (tid < PP) {
        float s = 0.f;
        for (int c = 0; c < CC; ++c) s = fmaf(f1L[c * PP + tid], vL[c], s);
        mrowL[tid] = s * inv1L[tid] * (1.0f / QQ);
    }
    if (tid < 31 * 16) {
        const int k = tid >> 4, sub = tid & 15;
        float s = 0.f;
        for (int q = sub; q < QQ; q += 16) s = fmaf(mcolL[q], W1[k * QQ + q], s);
        s += __shfl_xor(s, 1, 64); s += __shfl_xor(s, 2, 64);
        s += __shfl_xor(s, 4, 64); s += __shfl_xor(s, 8, 64);
        if (sub == 0) {
            float t = s + b1[k];
            t = (t - rm1[k]) * rsqrtf(rv1[k] + BN_EPS) * g1[k] + bb1[k];
            taL[k] = fmaxf(t, 0.f);
        }
    }
    __syncthreads();
    if (tid < 7 * 8) {
        const int k = tid >> 3, sub = tid & 7;
        float s = 0.f;
        for (int p = sub; p < PP; p += 8) s = fmaf(mrowL[p], W3[k * PP + p], s);
        s += __shfl_xor(s, 1, 64); s += __shfl_xor(s, 2, 64); s += __shfl_xor(s, 4, 64);
        if (sub == 0) {
            float t = s + b3[k];
            t = (t - rm3[k]) * rsqrtf(rv3[k] + BN_EPS) * g3[k] + bb3[k];
            tbL[k] = fmaxf(t, 0.f);
        }
    }
    __syncthreads();
    if (tid < PP) {
        float s = b4[tid];
#pragma unroll
        for (int k = 0; k < 7; ++k) s = fmaf(tbL[k], W4[tid * 7 + k], s);
        t2bL[tid] = s;
    }
    for (int q = tid; q < QQ; q += 512) {
        float s = b2[q];
#pragma unroll
        for (int k = 0; k < 31; ++k) s = fmaf(taL[k], W2[q * 31 + k], s);
        wgt_ws[lb * QP + q] = s * i2L[q];
    }
    __syncthreads();
    if (tid < CC) {
        float s = 0.f;
#pragma unroll
        for (int p = 0; p < PP; ++p) s = fmaf(inv1L[p] * t2bL[p], f1L[tid * PP + p], s);
        wb_ws[lb * CC + tid] = s;
    }
}

// ===== K5 xjoint: ONE xf sweep -> s2 partials + vb partials (r19-proven) ====
__global__ __launch_bounds__(256) void xjoint(
    const float* __restrict__ xf, const float* __restrict__ wb_ws,
    const float* __restrict__ wgt_ws,
    float* __restrict__ s2p, float* __restrict__ vbp)
{
    const int qg = blockIdx.x;       // 0..3
    const int ch = blockIdx.y;       // 0..1
    const int lb = blockIdx.z;
    const int tid  = threadIdx.x;
    const int lane = tid & 63;
    const int wave = tid >> 6;       // 0..3
    const int q  = qg * 256 + tid;
    const bool qv = (q < QQ);
    const int qc = qv ? q : QQ - 1;

    __shared__ float wbL[128];
    __shared__ float wgtL[256];
    __shared__ __align__(16) float tile[16 * 264];

    if (tid < 128) wbL[tid] = wb_ws[lb * CC + ch * 128 + tid];
    wgtL[tid] = qv ? wgt_ws[lb * QP + q] : 0.f;

    const float* __restrict__ base =
        xf + (size_t)lb * CC * QQ + (size_t)(ch * 128) * QQ + qc;
    float* __restrict__ vbpo = vbp + ((size_t)(lb * 8 + ch * 4 + qg)) * 128;

    float dwb = 0.f;
    for (int c0 = 0; c0 < 128; c0 += 16) {
        __syncthreads();
#pragma unroll
        for (int r = 0; r < 16; ++r)
            tile[r * 264 + tid] = base[(size_t)(c0 + r) * QQ];
        __syncthreads();
#pragma unroll
        for (int r = 0; r < 16; ++r)
            dwb = fmaf(wbL[c0 + r], tile[r * 264 + tid], dwb);
#pragma unroll
        for (int rr = 0; rr < 4; ++rr) {
            const int r = wave + rr * 4;
            float s = 0.f;
#pragma unroll
            for (int j = 0; j < 4; ++j)
                s = fmaf(tile[r * 264 + j * 64 + lane], wgtL[j * 64 + lane], s);
            for (int off = 32; off > 0; off >>= 1) s += __shfl_xor(s, off, 64);
            if (lane == 0) vbpo[c0 + r] = s;
        }
    }
    if (qv) s2p[((size_t)ch * NLB + lb) * QP + q] = dwb;
}

// ===== K6 fin: s1 from vb partials; s2 from partials; softmaxes =============
__global__ __launch_bounds__(512) void fin_kernel(
    const float* __restrict__ zf, const float* __restrict__ vbp,
    const float* __restrict__ inv1_ws, const float* __restrict__ s2p,
    const float* __restrict__ inv2_ws,
    float* __restrict__ att1_ws, float* __restrict__ att2_ws)
{
    const int lb = blockIdx.x;
    const int tid = threadIdx.x;
    const int lane = tid & 63;
    const int wv = tid >> 6;
    __shared__ float f1L[CC * PP];
    __shared__ float vbL[CC], inv1L[64], s1L[PP];
    __shared__ float s2L[QQ];
    __shared__ float redM[8], redS[8];

    const float* __restrict__ f1 = zf + (size_t)lb * CC * PP;
    for (int i = tid; i < CC * PP; i += 512) f1L[i] = f1[i];
    if (tid < CC) {
        const int ch = tid >> 7;
        const int co = tid & 127;
        float s = 0.f;
#pragma unroll
        for (int qg = 0; qg < 4; ++qg)
            s += vbp[((size_t)(lb * 8 + ch * 4 + qg)) * 128 + co];
        vbL[tid] = s;
    }
    if (tid >= 256 && tid < 320) inv1L[tid - 256] = inv1_ws[lb * 64 + tid - 256];
    for (int q = tid; q < QQ; q += 512)
        s2L[q] = (s2p[((size_t)0 * NLB + lb) * QP + q] +
                  s2p[((size_t)1 * NLB + lb) * QP + q]) *
                 inv2_ws[lb * QP + q] * (1.0f / PP) * TEMP_INV;
    __syncthreads();

    if (tid < PP) {
        float s = 0.f;
        for (int c = 0; c < CC; ++c) s = fmaf(f1L[c * PP + tid], vbL[c], s);
        s1L[tid] = s * inv1L[tid] * (1.0f / QQ) * TEMP_INV;
    }
    __syncthreads();

    if (wv == 0) {
        const float v = (lane < PP) ? s1L[lane] : -3.4e38f;
        float m = v;
        for (int off = 32; off > 0; off >>= 1) m = fmaxf(m, __shfl_xor(m, off, 64));
        const float e = (lane < PP) ? expf(v - m) : 0.f;
        float sum = e;
        for (int off = 32; off > 0; off >>= 1) sum += __shfl_xor(sum, off, 64);
        if (lane < PP) att1_ws[lb * PP + lane] = e / sum + 1.0f;
    }

    float lm = -3.4e38f;
    for (int q = tid; q < QQ; q += 512) lm = fmaxf(lm, s2L[q]);
    for (int off = 32; off > 0; off >>= 1) lm = fmaxf(lm, __shfl_xor(lm, off, 64));
    if (lane == 0) redM[wv] = lm;
    __syncthreads();
    float gm = redM[0];
#pragma unroll
    for (int i = 1; i < 8; ++i) gm = fmaxf(gm, redM[i]);
    float ls = 0.f;
    for (int q = tid; q < QQ; q += 512) ls += expf(s2L[q] - gm);
    for (int off = 32; off > 0; off >>= 1) ls += __shfl_xor(ls, off, 64);
    if (lane == 0) redS[wv] = ls;
    __syncthreads();
    float tot = 0.f;
#pragma unroll
    for (int i = 0; i < 8; ++i) tot += redS[i];
    const float rinv = 1.0f / tot;
    for (int q = tid; q < QQ; q += 512)
        att2_ws[lb * QQ + q] = expf(s2L[q] - gm) * rinv + 1.0f;
}

// ===== K7 scale_fused: both outputs in one launch ===========================
__global__ __launch_bounds__(256) void scale_fused(
    const float* __restrict__ zf, const float* __restrict__ xf,
    const float* __restrict__ att1, const float* __restrict__ att2,
    float* __restrict__ out1, float* __restrict__ out2,
    int n4_1, int n4_total)
{
    const int i = blockIdx.x * 256 + threadIdx.x;
    if (i >= n4_total) return;
    if (i < n4_1) {
        const float4 v = reinterpret_cast<const float4*>(zf)[i];
        const float* vv = reinterpret_cast<const float*>(&v);
        float4 o;
        float* ov = reinterpret_cast<float*>(&o);
        const int g = i * 4;
#pragma unroll
        for (int j = 0; j < 4; ++j) {
            const int gg = g + j;
            const int lb = gg / (CC * PP);
            const int x  = gg % PP;
            ov[j] = vv[j] * att1[lb * PP + x];
        }
        reinterpret_cast<float4*>(out1)[i] = o;
    } else {
        const int i2 = i - n4_1;
        const float4 v = reinterpret_cast<const float4*>(xf)[i2];
        const float* vv = reinterpret_cast<const float*>(&v);
        float4 o;
        float* ov = reinterpret_cast<float*>(&o);
        const int g = i2 * 4;
#pragma unroll
        for (int j = 0; j < 4; ++j) {
            const int gg = g + j;
            const int lb = gg / (CC * QQ);
            const int x  = gg % QQ;
            ov[j] = vv[j] * att2[lb * QQ + x];
        }
        reinterpret_cast<float4*>(out2)[i2] = o;
    }
}

extern "C" void kernel_launch(void* const* d_in, const int* in_sizes, int n_in,
                              void* d_out, int out_size, void* d_ws, size_t ws_size,
                              hipStream_t stream)
{
    const float* zf  = (const float*)d_in[0];
    const float* xf  = (const float*)d_in[1];
    const float* W1  = (const float*)d_in[2];
    const float* b1  = (const float*)d_in[3];
    const float* g1  = (const float*)d_in[4];
    const float* bb1 = (const float*)d_in[5];
    const float* rm1 = (const float*)d_in[6];
    const float* rv1 = (const float*)d_in[7];
    const float* W2  = (const float*)d_in[8];
    const float* b2  = (const float*)d_in[9];
    const float* W3  = (const float*)d_in[10];
    const float* b3  = (const float*)d_in[11];
    const float* g3  = (const float*)d_in[12];
    const float* bb3 = (const float*)d_in[13];
    const float* rm3 = (const float*)d_in[14];
    const float* rv3 = (const float*)d_in[15];
    const float* W4  = (const float*)d_in[16];
    const float* b4  = (const float*)d_in[17];

    float* ws = (float*)d_ws;
    float* w    = ws;                          // 96*256
    float* wb   = w    + (size_t)NLB * CC;     // 96*256
    float* inv1 = wb   + (size_t)NLB * CC;     // 96*64
    float* inv2 = inv1 + (size_t)NLB * 64;     // 96*1024
    float* wgt  = inv2 + (size_t)NLB * QP;     // 96*1024
    float* att1 = wgt  + (size_t)NLB * QP;     // 96*49
    float* att2 = att1 + (size_t)NLB * PP;     // 96*961
    float* ssp  = att2 + (size_t)NLB * QQ;     // 2*96*1024
    float* dcp  = ssp  + (size_t)2 * NLB * QP; // 2*96*1024
    float* s2p  = dcp  + (size_t)2 * NLB * QP; // 2*96*1024
    float* vp   = s2p  + (size_t)2 * NLB * QP; // 96*4*64
    float* vbp  = vp   + (size_t)NLB * 4 * 64; // 96*8*128

    float* out1 = (float*)d_out;
    float* out2 = out1 + N1;

    prep_z<<<NLB, 256, 0, stream>>>(zf, inv1, w);

    dim3 gqs(4, 2, NLB);
    xpass1<<<gqs, 256, 0, stream>>>(xf, w, ssp, dcp);

    dim3 gv(4, NLB);
    vpass_kernel<<<gv, 512, 0, stream>>>(xf, ssp, vp);

    mid_kernel<<<NLB, 512, 0, stream>>>(zf, vp, inv1, ssp, dcp,
        W1, b1, g1, bb1, rm1, rv1, W2, b2,
        W3, b3, g3, bb3, rm3, rv3, W4, b4,
        wgt, wb, inv2);

    xjoint<<<gqs, 256, 0, stream>>>(xf, wb, wgt, s2p, vbp);

    fin_kernel<<<NLB, 512, 0, stream>>>(zf, vbp, inv1, s2p, inv2, att1, att2);

    const int n4_1 = N1 / 4;
    const int n4_2 = N2 / 4;
    const int n4t = n4_1 + n4_2;
    scale_fused<<<(n4t + 255) / 256, 256, 0, stream>>>(
        zf, xf, att1, att2, out1, out2, n4_1, n4t);
}